// Round 4
// baseline (759.680 us; speedup 1.0000x reference)
//
#include <hip/hip_runtime.h>
#include <math.h>

#define B_ 8
#define Q_ 100
#define T_ 50
#define HW_ 65536
#define NSEG 128
#define SEG (HW_ / NSEG)    // 512 K per block
#define NK32 (SEG / 32)     // 16 K-steps of 32
#define NSTR 52             // N stride in ws (50 t + ssum col + pad)

// workspace layout (floats)
#define DSZ (B_ * Q_ * NSTR)       // 41600
#define WS_D1 0
#define WS_D2 DSZ
#define WS_SNEG (2 * DSZ)          // 800
#define WS_ST (2 * DSZ + B_ * Q_)  // 400
#define WS_TOTAL (2 * DSZ + B_ * Q_ + B_ * T_)

typedef __attribute__((ext_vector_type(8))) short bf16x8;
typedef __attribute__((ext_vector_type(4))) float f32x4;

__device__ __forceinline__ unsigned short f2bf(float f) {
    union { float f; unsigned u; } v; v.f = f;
    unsigned r = v.u + 0x7FFF + ((v.u >> 16) & 1);
    return (unsigned short)(r >> 16);
}

__global__ void zero_ws(float* ws) {
    int i = blockIdx.x * blockDim.x + threadIdx.x;
    if (i < WS_TOTAL) ws[i] = 0.f;
}

// LDS-free, barrier-free fused GEMM. Each wave: M-tiles {wave, wave+4} x all
// 4 N-tiles, fragments loaded straight from global in MFMA layout.
// Load-issue order: t first, x last; consume x first -> partial vmcnt waits.
__global__ __launch_bounds__(256, 4) void gemm_fused(const float* __restrict__ pred,
                                                     const int* __restrict__ tgt,
                                                     float* __restrict__ ws) {
    const int seg = blockIdx.x;
    const int b   = blockIdx.y;
    const int tid = threadIdx.x;
    const int wave = tid >> 6;
    const int lane = tid & 63;
    const int quad = lane >> 4;
    const int l16  = lane & 15;

    // A (x) pointers: rows clamped into [0, Q_) — garbage tiles never written
    const float* xptr[2];
#pragma unroll
    for (int mt = 0; mt < 2; ++mt) {
        int m = (wave + mt * 4) * 16 + l16;
        int mr = m < Q_ ? m : Q_ - 1;
        xptr[mt] = pred + ((size_t)b * Q_ + mr) * HW_ + (size_t)seg * SEG + quad * 8;
    }
    // B (t) pointers: rows clamped into [0, T_)
    const int* tptr[4];
    int ones[4];
#pragma unroll
    for (int nt = 0; nt < 4; ++nt) {
        int n = nt * 16 + l16;
        ones[nt] = (n == T_);          // the Sigma-sigmoid ones column
        int nr = n < T_ ? n : T_ - 1;
        tptr[nt] = tgt + ((size_t)b * T_ + nr) * HW_ + (size_t)seg * SEG + quad * 8;
    }

    f32x4 accx[2][4], accs[2][4];
#pragma unroll
    for (int mt = 0; mt < 2; ++mt)
#pragma unroll
        for (int nt = 0; nt < 4; ++nt) {
            accx[mt][nt] = (f32x4)(0.f);
            accs[mt][nt] = (f32x4)(0.f);
        }
    float sneg[2] = {0.f, 0.f};
    int stq[4] = {0, 0, 0, 0};

    float4 xrb[2][2][2];
    int4   trb[2][4][2];

    // issue t loads FIRST, x loads LAST
    auto loadraw = [&](int ch, float4 xr[2][2], int4 tr[4][2]) {
        const int k = ch * 32;
#pragma unroll
        for (int nt = 0; nt < 4; ++nt) {
            tr[nt][0] = *(const int4*)(tptr[nt] + k);
            tr[nt][1] = *(const int4*)(tptr[nt] + k + 4);
        }
#pragma unroll
        for (int mt = 0; mt < 2; ++mt) {
            xr[mt][0] = *(const float4*)(xptr[mt] + k);
            xr[mt][1] = *(const float4*)(xptr[mt] + k + 4);
        }
    };

    // consume x FIRST (long transcendental stretch), then t, then MFMAs
    auto compute = [&](float4 xr[2][2], int4 tr[4][2]) {
        bf16x8 xf[2], sf[2];
#pragma unroll
        for (int mt = 0; mt < 2; ++mt) {
            float sp = 0.f;
#pragma unroll
            for (int h = 0; h < 2; ++h)
#pragma unroll
                for (int e = 0; e < 4; ++e) {
                    float x = (&xr[mt][h].x)[e];
                    float ax = fabsf(x);
                    float ee = __expf(-ax);
                    float d = 1.f + ee;
                    float r1 = __builtin_amdgcn_rcpf(d);
                    float sg = (x >= 0.f) ? r1 : ee * r1;              // sigmoid
                    sp += fmaxf(x, 0.f) + 0.69314718056f * __log2f(d); // softplus
                    xf[mt][h * 4 + e] = (short)f2bf(x);
                    sf[mt][h * 4 + e] = (short)f2bf(sg);
                }
            sneg[mt] += sp;
        }
        bf16x8 tf[4];
#pragma unroll
        for (int nt = 0; nt < 4; ++nt) {
            int cnt = 0;
#pragma unroll
            for (int h = 0; h < 2; ++h)
#pragma unroll
                for (int e = 0; e < 4; ++e) {
                    int v = (&tr[nt][h].x)[e];
                    tf[nt][h * 4 + e] = (v || ones[nt]) ? (short)0x3F80 : (short)0;
                    cnt += v;
                }
            stq[nt] += cnt;
        }
#pragma unroll
        for (int mt = 0; mt < 2; ++mt)
#pragma unroll
            for (int nt = 0; nt < 4; ++nt) {
                accx[mt][nt] = __builtin_amdgcn_mfma_f32_16x16x32_bf16(xf[mt], tf[nt], accx[mt][nt], 0, 0, 0);
                accs[mt][nt] = __builtin_amdgcn_mfma_f32_16x16x32_bf16(sf[mt], tf[nt], accs[mt][nt], 0, 0, 0);
            }
    };

    loadraw(0, xrb[0], trb[0]);
#pragma unroll 2
    for (int ch = 0; ch < NK32; ++ch) {
        const int cb = ch & 1;
        if (ch + 1 < NK32) loadraw(ch + 1, xrb[cb ^ 1], trb[cb ^ 1]);
        compute(xrb[cb], trb[cb]);
    }

    // ---- epilogue ----
    // softplus row sums: reduce across the 4 quads (same l16)
#pragma unroll
    for (int mt = 0; mt < 2; ++mt) {
        float v = sneg[mt];
        v += __shfl_xor(v, 16);
        v += __shfl_xor(v, 32);
        int m = (wave + mt * 4) * 16 + l16;
        if (quad == 0 && m < Q_) atomicAdd(&ws[WS_SNEG + b * Q_ + m], v);
    }
    // t row sums (only wave 0's copy — it loaded the full t chunk)
    if (wave == 0) {
#pragma unroll
        for (int nt = 0; nt < 4; ++nt) {
            int vi = stq[nt];
            vi += __shfl_xor(vi, 16);
            vi += __shfl_xor(vi, 32);
            int n = nt * 16 + l16;
            if (quad == 0 && n < T_) atomicAdd(&ws[WS_ST + b * T_ + n], (float)vi);
        }
    }
    // D atomics; C/D layout: col = l16 (n), row-within-tile = quad*4 + r
#pragma unroll
    for (int mt = 0; mt < 2; ++mt) {
        int mtile = (wave + mt * 4) * 16;
#pragma unroll
        for (int nt = 0; nt < 4; ++nt) {
            int n = nt * 16 + l16;
#pragma unroll
            for (int r = 0; r < 4; ++r) {
                int m = mtile + quad * 4 + r;
                if (m < Q_) {
                    size_t idx = ((size_t)b * Q_ + m) * NSTR + n;
                    if (n < T_) atomicAdd(&ws[WS_D1 + idx], accx[mt][nt][r]);
                    if (n <= T_) atomicAdd(&ws[WS_D2 + idx], accs[mt][nt][r]);
                }
            }
        }
    }
}

__global__ void finalize(const float* __restrict__ ws, float* __restrict__ out) {
    int i = blockIdx.x * blockDim.x + threadIdx.x;
    if (i >= B_ * Q_ * T_) return;
    int b = i / (Q_ * T_);
    int r = i % (Q_ * T_);
    int q = r / T_;
    int t = r % T_;
    float dx   = ws[WS_D1 + ((size_t)b * Q_ + q) * NSTR + t];
    float ds   = ws[WS_D2 + ((size_t)b * Q_ + q) * NSTR + t];
    float ssum = ws[WS_D2 + ((size_t)b * Q_ + q) * NSTR + T_];
    float st   = ws[WS_ST + b * T_ + t];
    float sneg = ws[WS_SNEG + b * Q_ + q];
    float ce = (sneg - dx) * (1.f / (float)HW_);
    float dice = 1.f - (2.f * ds + 1.f) / (ssum + st + 1.f);
    out[i] = ce + dice;
}

extern "C" void kernel_launch(void* const* d_in, const int* in_sizes, int n_in,
                              void* d_out, int out_size, void* d_ws, size_t ws_size,
                              hipStream_t stream) {
    const float* pred = (const float*)d_in[0];
    const int* tgt = (const int*)d_in[1];
    float* ws = (float*)d_ws;
    float* out = (float*)d_out;

    zero_ws<<<(WS_TOTAL + 255) / 256, 256, 0, stream>>>(ws);
    dim3 g(NSEG, B_, 1);
    gemm_fused<<<g, 256, 0, stream>>>(pred, tgt, ws);
    finalize<<<(B_ * Q_ * T_ + 255) / 256, 256, 0, stream>>>(ws, out);
}

// Round 5
// 413.026 us; speedup vs baseline: 1.8393x; 1.8393x over previous
//
#include <hip/hip_runtime.h>
#include <math.h>

#define B_ 8
#define Q_ 100
#define T_ 50
#define HW_ 65536
#define NSEG 128
#define SEG (HW_ / NSEG)    // 512 K per block
#define NK32 (SEG / 32)     // 16 K-steps of 32
#define NSTR 52             // N stride in ws (50 t + ssum col + pad)

// workspace layout (floats)
#define DSZ (B_ * Q_ * NSTR)       // 41600
#define WS_D1 0
#define WS_D2 DSZ
#define WS_SNEG (2 * DSZ)          // 800
#define WS_ST (2 * DSZ + B_ * Q_)  // 400
#define WS_TOTAL (2 * DSZ + B_ * Q_ + B_ * T_)

typedef __attribute__((ext_vector_type(8))) short bf16x8;
typedef __attribute__((ext_vector_type(4))) float f32x4;

__device__ __forceinline__ unsigned short f2bf(float f) {
    union { float f; unsigned u; } v; v.f = f;
    unsigned r = v.u + 0x7FFF + ((v.u >> 16) & 1);
    return (unsigned short)(r >> 16);
}

__global__ void zero_ws(float* ws) {
    int i = blockIdx.x * blockDim.x + threadIdx.x;
    if (i < WS_TOTAL) ws[i] = 0.f;
}

// LDS-free, barrier-free fused GEMM. Each wave: M-tiles {wave, wave+4} x all
// 4 N-tiles, fragments loaded straight from global in MFMA layout.
// Load-issue order: t first, x last; consume x first -> partial vmcnt waits.
// NOTE: __launch_bounds__(256,2) — NOT 4. Forcing 4 caps VGPR at 64 and the
// ~120-VGPR body spills to scratch (R4: WRITE_SIZE 28MB->1.1GB, 527us).
// At natural 120 VGPR the HW still reaches 4 waves/SIMD (512/120 = 4).
__global__ __launch_bounds__(256, 2) void gemm_fused(const float* __restrict__ pred,
                                                     const int* __restrict__ tgt,
                                                     float* __restrict__ ws) {
    const int seg = blockIdx.x;
    const int b   = blockIdx.y;
    const int tid = threadIdx.x;
    const int wave = tid >> 6;
    const int lane = tid & 63;
    const int quad = lane >> 4;
    const int l16  = lane & 15;

    // A (x) pointers: rows clamped into [0, Q_) — garbage tiles never written
    const float* xptr[2];
#pragma unroll
    for (int mt = 0; mt < 2; ++mt) {
        int m = (wave + mt * 4) * 16 + l16;
        int mr = m < Q_ ? m : Q_ - 1;
        xptr[mt] = pred + ((size_t)b * Q_ + mr) * HW_ + (size_t)seg * SEG + quad * 8;
    }
    // B (t) pointers: rows clamped into [0, T_)
    const int* tptr[4];
    int ones[4];
#pragma unroll
    for (int nt = 0; nt < 4; ++nt) {
        int n = nt * 16 + l16;
        ones[nt] = (n == T_);          // the Sigma-sigmoid ones column
        int nr = n < T_ ? n : T_ - 1;
        tptr[nt] = tgt + ((size_t)b * T_ + nr) * HW_ + (size_t)seg * SEG + quad * 8;
    }

    f32x4 accx[2][4], accs[2][4];
#pragma unroll
    for (int mt = 0; mt < 2; ++mt)
#pragma unroll
        for (int nt = 0; nt < 4; ++nt) {
            accx[mt][nt] = (f32x4)(0.f);
            accs[mt][nt] = (f32x4)(0.f);
        }
    float sneg[2] = {0.f, 0.f};
    int stq[4] = {0, 0, 0, 0};

    float4 xrb[2][2][2];
    int4   trb[2][4][2];

    // issue t loads FIRST, x loads LAST
    auto loadraw = [&](int ch, float4 xr[2][2], int4 tr[4][2]) {
        const int k = ch * 32;
#pragma unroll
        for (int nt = 0; nt < 4; ++nt) {
            tr[nt][0] = *(const int4*)(tptr[nt] + k);
            tr[nt][1] = *(const int4*)(tptr[nt] + k + 4);
        }
#pragma unroll
        for (int mt = 0; mt < 2; ++mt) {
            xr[mt][0] = *(const float4*)(xptr[mt] + k);
            xr[mt][1] = *(const float4*)(xptr[mt] + k + 4);
        }
    };

    // consume x FIRST (long transcendental stretch), then t, then MFMAs
    auto compute = [&](float4 xr[2][2], int4 tr[4][2]) {
        bf16x8 xf[2], sf[2];
#pragma unroll
        for (int mt = 0; mt < 2; ++mt) {
            float sp = 0.f;
#pragma unroll
            for (int h = 0; h < 2; ++h)
#pragma unroll
                for (int e = 0; e < 4; ++e) {
                    float x = (&xr[mt][h].x)[e];
                    float ax = fabsf(x);
                    float ee = __expf(-ax);
                    float d = 1.f + ee;
                    float r1 = __builtin_amdgcn_rcpf(d);
                    float sg = (x >= 0.f) ? r1 : ee * r1;              // sigmoid
                    sp += fmaxf(x, 0.f) + 0.69314718056f * __log2f(d); // softplus
                    xf[mt][h * 4 + e] = (short)f2bf(x);
                    sf[mt][h * 4 + e] = (short)f2bf(sg);
                }
            sneg[mt] += sp;
        }
        bf16x8 tf[4];
#pragma unroll
        for (int nt = 0; nt < 4; ++nt) {
            int cnt = 0;
#pragma unroll
            for (int h = 0; h < 2; ++h)
#pragma unroll
                for (int e = 0; e < 4; ++e) {
                    int v = (&tr[nt][h].x)[e];
                    tf[nt][h * 4 + e] = (v || ones[nt]) ? (short)0x3F80 : (short)0;
                    cnt += v;
                }
            stq[nt] += cnt;
        }
#pragma unroll
        for (int mt = 0; mt < 2; ++mt)
#pragma unroll
            for (int nt = 0; nt < 4; ++nt) {
                accx[mt][nt] = __builtin_amdgcn_mfma_f32_16x16x32_bf16(xf[mt], tf[nt], accx[mt][nt], 0, 0, 0);
                accs[mt][nt] = __builtin_amdgcn_mfma_f32_16x16x32_bf16(sf[mt], tf[nt], accs[mt][nt], 0, 0, 0);
            }
    };

    loadraw(0, xrb[0], trb[0]);
#pragma unroll 2
    for (int ch = 0; ch < NK32; ++ch) {
        const int cb = ch & 1;
        if (ch + 1 < NK32) loadraw(ch + 1, xrb[cb ^ 1], trb[cb ^ 1]);
        compute(xrb[cb], trb[cb]);
    }

    // ---- epilogue ----
    // softplus row sums: reduce across the 4 quads (same l16)
#pragma unroll
    for (int mt = 0; mt < 2; ++mt) {
        float v = sneg[mt];
        v += __shfl_xor(v, 16);
        v += __shfl_xor(v, 32);
        int m = (wave + mt * 4) * 16 + l16;
        if (quad == 0 && m < Q_) atomicAdd(&ws[WS_SNEG + b * Q_ + m], v);
    }
    // t row sums (only wave 0's copy — it loaded the full t chunk)
    if (wave == 0) {
#pragma unroll
        for (int nt = 0; nt < 4; ++nt) {
            int vi = stq[nt];
            vi += __shfl_xor(vi, 16);
            vi += __shfl_xor(vi, 32);
            int n = nt * 16 + l16;
            if (quad == 0 && n < T_) atomicAdd(&ws[WS_ST + b * T_ + n], (float)vi);
        }
    }
    // D atomics; C/D layout: col = l16 (n), row-within-tile = quad*4 + r
#pragma unroll
    for (int mt = 0; mt < 2; ++mt) {
        int mtile = (wave + mt * 4) * 16;
#pragma unroll
        for (int nt = 0; nt < 4; ++nt) {
            int n = nt * 16 + l16;
#pragma unroll
            for (int r = 0; r < 4; ++r) {
                int m = mtile + quad * 4 + r;
                if (m < Q_) {
                    size_t idx = ((size_t)b * Q_ + m) * NSTR + n;
                    if (n < T_) atomicAdd(&ws[WS_D1 + idx], accx[mt][nt][r]);
                    if (n <= T_) atomicAdd(&ws[WS_D2 + idx], accs[mt][nt][r]);
                }
            }
        }
    }
}

__global__ void finalize(const float* __restrict__ ws, float* __restrict__ out) {
    int i = blockIdx.x * blockDim.x + threadIdx.x;
    if (i >= B_ * Q_ * T_) return;
    int b = i / (Q_ * T_);
    int r = i % (Q_ * T_);
    int q = r / T_;
    int t = r % T_;
    float dx   = ws[WS_D1 + ((size_t)b * Q_ + q) * NSTR + t];
    float ds   = ws[WS_D2 + ((size_t)b * Q_ + q) * NSTR + t];
    float ssum = ws[WS_D2 + ((size_t)b * Q_ + q) * NSTR + T_];
    float st   = ws[WS_ST + b * T_ + t];
    float sneg = ws[WS_SNEG + b * Q_ + q];
    float ce = (sneg - dx) * (1.f / (float)HW_);
    float dice = 1.f - (2.f * ds + 1.f) / (ssum + st + 1.f);
    out[i] = ce + dice;
}

extern "C" void kernel_launch(void* const* d_in, const int* in_sizes, int n_in,
                              void* d_out, int out_size, void* d_ws, size_t ws_size,
                              hipStream_t stream) {
    const float* pred = (const float*)d_in[0];
    const int* tgt = (const int*)d_in[1];
    float* ws = (float*)d_ws;
    float* out = (float*)d_out;

    zero_ws<<<(WS_TOTAL + 255) / 256, 256, 0, stream>>>(ws);
    dim3 g(NSEG, B_, 1);
    gemm_fused<<<g, 256, 0, stream>>>(pred, tgt, ws);
    finalize<<<(B_ * Q_ * T_ + 255) / 256, 256, 0, stream>>>(ws, out);
}